// Round 5
// baseline (118.357 us; speedup 1.0000x reference)
//
#include <hip/hip_runtime.h>
#include <stdint.h>

#define N_NODES 8192
#define NE      131072
#define DCH     128
#define WPR     256          // 32-bit words per bitmap row
#define MAXC    128          // per-node neighbor capacity (deg ~ Poisson(32))
#define EPS     1e-5f

// ---------------------------------------------------------------------------
// Fused dispatch: blocks [0,512) build the symmetric adjacency bitmap + exact
// deduped degree; blocks [512,768) compute z = x @ W. The two halves are
// independent (edge writes bm/deg; gemm reads x,W writes z) -> no sync needed.
__global__ __launch_bounds__(256) void build_gemm_kernel(
    const void*  __restrict__ ei_raw,
    const float* __restrict__ X,
    const float* __restrict__ W,
    uint32_t* __restrict__ bm,
    int*      __restrict__ deg,
    float*    __restrict__ z)
{
    int t = threadIdx.x;
    if (blockIdx.x < 512) {
        // ---- edge path: atomicOr dedups+symmetrizes; old-value test gives
        // exact deduped degree (self-edge bit counted once, matching popcount).
        int lane = t & 63;
        const long long* p64 = (const long long*)ei_raw;
        const int*       p32 = (const int*)ei_raw;
        // layout detect: int32-packed data puts node ids in qword high halves
        bool is64 = __all((unsigned long long)p64[lane] < (unsigned long long)N_NODES);
        int e = blockIdx.x * 256 + t;
        int r, c;
        if (is64) { r = (int)p64[e]; c = (int)p64[NE + e]; }
        else      { r = p32[e];      c = p32[NE + e]; }
        uint32_t mc = 1u << (c & 31), mr = 1u << (r & 31);
        uint32_t o1 = atomicOr(&bm[r * WPR + (c >> 5)], mc);
        if (!(o1 & mc)) atomicAdd(&deg[r], 1);
        uint32_t o2 = atomicOr(&bm[c * WPR + (r >> 5)], mr);
        if (!(o2 & mr)) atomicAdd(&deg[c], 1);
    } else {
        // ---- gemm path: z = X @ W (no dinv; applied later per-neighbor).
        // 64x64 tile, 4x4 per thread, f32 VALU (no fp32 MFMA on CDNA4).
        __shared__ float sA[64][132];
        int bx = blockIdx.x - 512;
        int row0 = (bx >> 1) * 64;
        int col0 = (bx & 1) * 64;
        {
            int k4 = t & 31;
            int r  = t >> 5;
            #pragma unroll
            for (int p = 0; p < 8; ++p) {
                float4 v = *(const float4*)&X[(size_t)(row0 + r + p * 8) * DCH + k4 * 4];
                *(float4*)&sA[r + p * 8][k4 * 4] = v;
            }
        }
        __syncthreads();
        int tx = t & 15, ty = t >> 4;
        int cg = col0 + tx * 4;
        int r0 = ty * 4;
        float acc[4][4] = {};
        #pragma unroll 4
        for (int k = 0; k < DCH; ++k) {
            float4 w = *(const float4*)&W[(size_t)k * DCH + cg];
            float a0 = sA[r0 + 0][k];
            float a1 = sA[r0 + 1][k];
            float a2 = sA[r0 + 2][k];
            float a3 = sA[r0 + 3][k];
            acc[0][0] += a0 * w.x; acc[0][1] += a0 * w.y; acc[0][2] += a0 * w.z; acc[0][3] += a0 * w.w;
            acc[1][0] += a1 * w.x; acc[1][1] += a1 * w.y; acc[1][2] += a1 * w.z; acc[1][3] += a1 * w.w;
            acc[2][0] += a2 * w.x; acc[2][1] += a2 * w.y; acc[2][2] += a2 * w.z; acc[2][3] += a2 * w.w;
            acc[3][0] += a3 * w.x; acc[3][1] += a3 * w.y; acc[3][2] += a3 * w.z; acc[3][3] += a3 * w.w;
        }
        #pragma unroll
        for (int i = 0; i < 4; ++i) {
            float4 o;
            o.x = acc[i][0]; o.y = acc[i][1]; o.z = acc[i][2]; o.w = acc[i][3];
            *(float4*)&z[(size_t)(row0 + r0 + i) * DCH + cg] = o;
        }
    }
}

// ---------------------------------------------------------------------------
// out[n] = dinv_n * ( sum_j dinv_j * z[j] + dinv_n * z[n] ) + bias
// One wave per node. Bitmap row -> LDS-compacted index list (shuffle prefix
// scan), then unroll-8 gather with 8 independent float2 accumulators.
// dinv_j recomputed per neighbor from the L1-hot deg table (wave-uniform:
// scalar load + short VALU sequence).
__global__ __launch_bounds__(256) void aggregate_kernel(
    const uint4* __restrict__ bm4,
    const int*   __restrict__ deg,
    const float* __restrict__ z,
    const float* __restrict__ bias,
    float*       __restrict__ out)
{
    __shared__ uint16_t slist[4][MAXC];   // 1 KB
    int w    = threadIdx.x >> 6;
    int lane = threadIdx.x & 63;
    int node = blockIdx.x * 4 + w;

    uint4 b = bm4[(size_t)node * 64 + lane];
    int c = __popc(b.x) + __popc(b.y) + __popc(b.z) + __popc(b.w);
    int pre = c;
    #pragma unroll
    for (int d = 1; d < 64; d <<= 1) {
        int v = __shfl_up(pre, d);
        if (lane >= d) pre += v;
    }
    int total = __shfl(pre, 63);          // = deg[node] (deduped popcount)
    int excl  = pre - c;

    // emit set-bit indices (wave-private LDS; same-wave ds ordering suffices)
    {
        uint32_t wd[4] = {b.x, b.y, b.z, b.w};
        int basebit = lane * 128;
        int o = excl;
        #pragma unroll
        for (int m = 0; m < 4; ++m) {
            uint32_t v = wd[m];
            while (v) {
                int bb = __ffs(v) - 1; v &= v - 1;
                if (o < MAXC) slist[w][o] = (uint16_t)(basebit + m * 32 + bb);
                ++o;
            }
        }
    }
    int cap  = total > MAXC ? MAXC : total;
    int kpad = (cap + 7) & ~7;
    int p = cap + lane;                   // pad to x8 with self (dj forced 0)
    if (p < kpad) slist[w][p] = (uint16_t)node;

    const float2* z2 = (const float2*)z;
    float dn = 1.0f / sqrtf((float)total + 1.0f + EPS);

    float2 self = z2[(size_t)node * 64 + lane];
    float2 a0, a1 = {0,0}, a2 = {0,0}, a3 = {0,0}, a4 = {0,0}, a5 = {0,0}, a6 = {0,0}, a7 = {0,0};
    a0.x = dn * self.x; a0.y = dn * self.y;           // +I self term

    for (int k = 0; k < kpad; k += 8) {
        #define STEP(i, AX) {                                                        \
            int idx = k + i;                                                         \
            int j = __builtin_amdgcn_readfirstlane((int)slist[w][idx]);              \
            float dj = (idx < cap) ? 1.0f / sqrtf((float)deg[j] + 1.0f + EPS) : 0.f; \
            float2 q = z2[(size_t)j * 64 + lane];                                    \
            AX.x += dj * q.x; AX.y += dj * q.y; }
        STEP(0, a0) STEP(1, a1) STEP(2, a2) STEP(3, a3)
        STEP(4, a4) STEP(5, a5) STEP(6, a6) STEP(7, a7)
        #undef STEP
    }

    float2 bb = ((const float2*)bias)[lane];
    float2 r;
    r.x = dn * (((a0.x + a1.x) + (a2.x + a3.x)) + ((a4.x + a5.x) + (a6.x + a7.x))) + bb.x;
    r.y = dn * (((a0.y + a1.y) + (a2.y + a3.y)) + ((a4.y + a5.y) + (a6.y + a7.y))) + bb.y;
    ((float2*)out)[(size_t)node * 64 + lane] = r;
}

// ---------------------------------------------------------------------------
extern "C" void kernel_launch(void* const* d_in, const int* in_sizes, int n_in,
                              void* d_out, int out_size, void* d_ws, size_t ws_size,
                              hipStream_t stream) {
    const float* xp  = (const float*)d_in[0];
    const void*  eip = d_in[1];
    const float* Wp  = (const float*)d_in[2];
    const float* bp  = (const float*)d_in[3];
    float*       op  = (float*)d_out;

    uint8_t* ws = (uint8_t*)d_ws;
    uint32_t* bmp  = (uint32_t*)ws;                                          // 8 MB
    int*      degp = (int*)     (ws + (size_t)8 * 1024 * 1024);              // 32 KB
    float*    zp   = (float*)   (ws + (size_t)8 * 1024 * 1024 + 32 * 1024);  // 4 MB

    // one fill covers bitmap + degree (contiguous)
    hipMemsetAsync(bmp, 0, (size_t)8 * 1024 * 1024 + 32 * 1024, stream);
    build_gemm_kernel<<<768, 256, 0, stream>>>(eip, xp, Wp, bmp, degp, zp);
    aggregate_kernel<<<N_NODES / 4, 256, 0, stream>>>((const uint4*)bmp, degp, zp, bp, op);
}